// Round 5
// baseline (165.451 us; speedup 1.0000x reference)
//
#include <hip/hip_runtime.h>
#include <hip/hip_bf16.h>

// ---------------------------------------------------------------------------
// MultiHeadAttention: feats L2-norm + clamp(coords) concat -> per-head QKV
// (DIN=259, HD=32, H=8) -> softmax attention (N=4096, clip +-100, /(sum+1e-6))
// -> output proj + bias + residual.
// Precision: hi/lo bf16 split (3-MFMA fp32 emulation) for QKV proj and QK^T;
// bf16 P and bf16 V for PV; plain bf16 for output proj.
// Attention: swapped-operand QK^T (S^T = K.Q^T) so softmax is lane-local,
// Q pre-scaled by scale*log2e (scores land in log2 domain), PV via 16x16x16
// MFMA (B-frag == S^T D-frag layout), split-K 4 waves/block + LDS merge.
// KBLK=64 keeps VGPR <= 64 so 8 waves/SIMD are resident (m69 granularity).
// ---------------------------------------------------------------------------

using s8  = __attribute__((ext_vector_type(8))) short;   // 8 x bf16 (4 VGPR)
using s4v = __attribute__((ext_vector_type(4))) short;   // 4 x bf16 (2 VGPR)
using f4  = __attribute__((ext_vector_type(4))) float;   // MFMA C/D
typedef unsigned short u16;
typedef unsigned int   u32;

#define NPTS 4096
#define NH   8
#define HD   32
#define DIN  259
#define DINP 288       // padded K-dim for QKV GEMM (9 x 32)
#define COUT 768       // 3*NH*HD, col c = s*256 + h*32 + hd (s: 0=q,1=k,2=v)
#define KBLK 64        // attention keys per inner iteration (VGPR budget)
#define KSPLIT 4       // waves per block, each takes NPTS/KSPLIT keys

// scale * log2(e): QK^T in log2 domain (monotone, identical softmax)
#define SCL2  (0.17677669529663687f * 1.4426950408889634f)
#define CLIP2 (100.0f * 1.4426950408889634f)

#define MFMA32(a, b, c) __builtin_amdgcn_mfma_f32_16x16x32_bf16((a), (b), (c), 0, 0, 0)

#if __has_builtin(__builtin_amdgcn_mfma_f32_16x16x16bf16_1k)
#define HAVE_MFMA16 1
#define MFMA16(a, b, c) __builtin_amdgcn_mfma_f32_16x16x16bf16_1k((a), (b), (c), 0, 0, 0)
#else
#define HAVE_MFMA16 0
#endif

#if __has_builtin(__builtin_amdgcn_exp2f)
#define EXP2(x) __builtin_amdgcn_exp2f(x)
#else
#define EXP2(x) exp2f(x)
#endif

__device__ __forceinline__ u16 f2bf(float f) {           // RNE, for cold paths
    u32 u = __float_as_uint(f);
    u32 r = u + 0x7FFFu + ((u >> 16) & 1u);
    return (u16)(r >> 16);
}
__device__ __forceinline__ float bf2f(u16 h) { return __uint_as_float(((u32)h) << 16); }
__device__ __forceinline__ void splitbf(float v, u16& hi, u16& lo) {
    hi = f2bf(v);
    lo = f2bf(v - bf2f(hi));
}
__device__ __forceinline__ u16 cvt1(float f) {           // native convert (RNE)
    __hip_bfloat16 b = __float2bfloat16(f);
    return *reinterpret_cast<u16*>(&b);
}
__device__ __forceinline__ s8 ld8(const u16* p) { return *reinterpret_cast<const s8*>(p); }
__device__ __forceinline__ u32 bfpair(float a, float b) {
    return (u32)cvt1(a) | ((u32)cvt1(b) << 16);
}

// ---------------------------------------------------------------------------
// Phase 0a: build transposed+split QKV weight matrix Wt[COUT][DINP]
// ---------------------------------------------------------------------------
__global__ void k_wprep(const float* __restrict__ wq, const float* __restrict__ wk,
                        const float* __restrict__ wv,
                        u16* __restrict__ wtHi, u16* __restrict__ wtLo) {
    int c = blockIdx.x;                   // 0..767
    int s = c >> 8, h = (c >> 5) & 7, hd = c & 31;
    const float* w = (s == 0) ? wq : (s == 1) ? wk : wv;
    for (int k = threadIdx.x; k < DINP; k += blockDim.x) {
        float val = (k < DIN) ? w[(h * DIN + k) * HD + hd] : 0.0f;
        u16 hi, lo; splitbf(val, hi, lo);
        wtHi[c * DINP + k] = hi;
        wtLo[c * DINP + k] = lo;
    }
}

// ---------------------------------------------------------------------------
// Phase 0b: woT[c][k] = wo[k][c] (bf16)
// ---------------------------------------------------------------------------
__global__ void k_woprep(const float* __restrict__ wo, u16* __restrict__ woT) {
    int c = blockIdx.x;
    int k = threadIdx.x;                  // blockDim = 256
    woT[c * 256 + k] = f2bf(wo[k * 256 + c]);
}

// ---------------------------------------------------------------------------
// Phase 1: featurize. One 64-lane wave per row.
// ---------------------------------------------------------------------------
__global__ __launch_bounds__(64) void k_featurize(const float* __restrict__ x,
                                                  const int* __restrict__ coords,
                                                  u16* __restrict__ xcHi,
                                                  u16* __restrict__ xcLo) {
    int row = blockIdx.x;
    int l = threadIdx.x;
    f4 v = *reinterpret_cast<const f4*>(x + row * 256 + 4 * l);
    float ss = v[0] * v[0] + v[1] * v[1] + v[2] * v[2] + v[3] * v[3];
#pragma unroll
    for (int m = 1; m < 64; m <<= 1) ss += __shfl_xor(ss, m);
    float inv = 1.0f / (sqrtf(ss) + 1e-6f);
#pragma unroll
    for (int j = 0; j < 4; ++j) {
        u16 hi, lo; splitbf(v[j] * inv, hi, lo);
        xcHi[row * DINP + 4 * l + j] = hi;
        xcLo[row * DINP + 4 * l + j] = lo;
    }
    if (l < 32) {
        int col = 256 + l;
        float val = 0.0f;
        if (col < DIN) {
            float c = (float)coords[row * 3 + (col - 256)];
            val = fminf(fmaxf(c, -100.0f), 100.0f);
        }
        u16 hi, lo; splitbf(val, hi, lo);
        xcHi[row * DINP + col] = hi;
        xcLo[row * DINP + col] = lo;
    }
}

// ---------------------------------------------------------------------------
// Phase 2: QKV GEMM  [4096 x DINP] x [DINP x 768] with 3-MFMA emulation.
// q (pre-scaled by SCL2), k row-major [h][n][hd] (hi/lo);
// v tiled [h][n>>4][hd][n&15] (bf16).
// ---------------------------------------------------------------------------
__global__ __launch_bounds__(256) void k_qkv(
        const u16* __restrict__ xcHi, const u16* __restrict__ xcLo,
        const u16* __restrict__ wtHi, const u16* __restrict__ wtLo,
        const float* __restrict__ bq, const float* __restrict__ bk,
        const float* __restrict__ bv,
        u16* __restrict__ qHi, u16* __restrict__ qLo,
        u16* __restrict__ kHi, u16* __restrict__ kLo,
        u16* __restrict__ vt2) {
    int w = threadIdx.x >> 6, l = threadIdx.x & 63;
    int lr = l & 15, lg = l >> 4;
    int r0 = blockIdx.x * 64 + w * 16;    // wave's row base
    int c0 = blockIdx.y * 64;             // block's col base

    f4 acc[4] = {};
    const u16* aH = xcHi + (r0 + lr) * DINP + lg * 8;
    const u16* aL = xcLo + (r0 + lr) * DINP + lg * 8;
#pragma unroll
    for (int kk = 0; kk < 9; ++kk) {
        s8 ah = ld8(aH + kk * 32);
        s8 al = ld8(aL + kk * 32);
#pragma unroll
        for (int ct = 0; ct < 4; ++ct) {
            int c = c0 + ct * 16 + lr;
            s8 bh = ld8(wtHi + c * DINP + kk * 32 + lg * 8);
            s8 bl = ld8(wtLo + c * DINP + kk * 32 + lg * 8);
            acc[ct] = MFMA32(al, bh, acc[ct]);
            acc[ct] = MFMA32(ah, bl, acc[ct]);
            acc[ct] = MFMA32(ah, bh, acc[ct]);
        }
    }
#pragma unroll
    for (int ct = 0; ct < 4; ++ct) {
        int c = c0 + ct * 16 + lr;
        int s = c >> 8, h = (c >> 5) & 7, hd = c & 31;
        float bias = ((s == 0) ? bq : (s == 1) ? bk : bv)[h * HD + hd];
#pragma unroll
        for (int r = 0; r < 4; ++r) {
            int n = r0 + lg * 4 + r;
            float val = acc[ct][r] + bias;
            if (s == 0) {
                u16 hi, lo; splitbf(val * SCL2, hi, lo);   // pre-scaled Q
                qHi[(h * NPTS + n) * HD + hd] = hi;
                qLo[(h * NPTS + n) * HD + hd] = lo;
            } else if (s == 1) {
                u16 hi, lo; splitbf(val, hi, lo);
                kHi[(h * NPTS + n) * HD + hd] = hi;
                kLo[(h * NPTS + n) * HD + hd] = lo;
            } else {
                // tiled V^T: [h][key tile][hd][key%16]
                vt2[((size_t)(h * 256 + (n >> 4)) * 32 + hd) * 16 + (n & 15)] = f2bf(val);
            }
        }
    }
}

// ---------------------------------------------------------------------------
// Phase 3: attention, split-K flash-decoding. Block = 4 waves on one
// (head, 16 q-rows); wave w handles keys [w*1024, w*1024+1024) in 16 iters
// of 64 keys. Swapped QK^T (log2-domain scores), lane-local softmax, PV via
// 16x16x16 MFMA. LDS merge of {m, sum, O}; wave 0 writes.
// blockIdx&7 = head -> per-XCD L2 holds one head's K/V.
// ---------------------------------------------------------------------------
__global__ __launch_bounds__(256, 8) void k_attn(
        const u16* __restrict__ qHi, const u16* __restrict__ qLo,
        const u16* __restrict__ kHi, const u16* __restrict__ kLo,
        const u16* __restrict__ vt2,
        u16* __restrict__ catH) {
    __shared__ float cmb[KSPLIT][64][13];  // {m,sum,o0[4],o1[4]} stride 13
    int b = blockIdx.x;
    int h = b & 7;                        // head -> XCD affinity
    int qb = b >> 3;                      // 0..255
    int w = threadIdx.x >> 6;             // key-split index
    int l = threadIdx.x & 63, lr = l & 15, lg = l >> 4;

    size_t qoff = (size_t)(h * NPTS + qb * 16 + lr) * HD + lg * 8;
    s8 qh = ld8(qHi + qoff);
    s8 ql = ld8(qLo + qoff);

    float m = -1.0e30f, sum = 0.0f;
    f4 o0 = {}, o1 = {};

#pragma unroll 2
    for (int kb = w * (NPTS / KSPLIT / KBLK); kb < (w + 1) * (NPTS / KSPLIT / KBLK); ++kb) {
        int kr0 = kb * KBLK;
        // S^T tiles: st[kt] holds S^T[key = kt*16 + lg*4 + r][q = lr], log2 domain
        f4 st[4];
#pragma unroll
        for (int kt = 0; kt < 4; ++kt) {
            size_t koff = (size_t)(h * NPTS + kr0 + kt * 16 + lr) * HD + lg * 8;
            s8 kh = ld8(kHi + koff);
            s8 kl = ld8(kLo + koff);
            f4 a = {};
            a = MFMA32(kl, qh, a);
            a = MFMA32(kh, ql, a);
            a = MFMA32(kh, qh, a);
            st[kt] = a;
        }
        // upper clip only (lower clip provably inert for softmax output)
#pragma unroll
        for (int kt = 0; kt < 4; ++kt)
#pragma unroll
            for (int r = 0; r < 4; ++r) st[kt][r] = fminf(st[kt][r], CLIP2);
        // row max: in-lane tree over 16 keys + butterfly across 4 lane groups
        float t0 = fmaxf(fmaxf(st[0][0], st[0][1]), fmaxf(st[0][2], st[0][3]));
        float t1 = fmaxf(fmaxf(st[1][0], st[1][1]), fmaxf(st[1][2], st[1][3]));
        float t2 = fmaxf(fmaxf(st[2][0], st[2][1]), fmaxf(st[2][2], st[2][3]));
        float t3 = fmaxf(fmaxf(st[3][0], st[3][1]), fmaxf(st[3][2], st[3][3]));
        float tm = fmaxf(fmaxf(t0, t1), fmaxf(t2, t3));
        tm = fmaxf(tm, __shfl_xor(tm, 16));
        tm = fmaxf(tm, __shfl_xor(tm, 32));
        float mn = fmaxf(m, tm);
        float fac = EXP2(m - mn);
        m = mn;
        sum *= fac;
#pragma unroll
        for (int r = 0; r < 4; ++r) { o0[r] *= fac; o1[r] *= fac; }
        // p = 2^(s-m), partial sums (4 parallel chains)
        float ps0 = 0.0f, ps1 = 0.0f, ps2 = 0.0f, ps3 = 0.0f;
#pragma unroll
        for (int kt = 0; kt < 4; ++kt) {
            float p0 = EXP2(st[kt][0] - m); st[kt][0] = p0; ps0 += p0;
            float p1 = EXP2(st[kt][1] - m); st[kt][1] = p1; ps1 += p1;
            float p2 = EXP2(st[kt][2] - m); st[kt][2] = p2; ps2 += p2;
            float p3 = EXP2(st[kt][3] - m); st[kt][3] = p3; ps3 += p3;
        }
        float ps = (ps0 + ps1) + (ps2 + ps3);
        ps += __shfl_xor(ps, 16);
        ps += __shfl_xor(ps, 32);
        sum += ps;

        // PV: O^T += V^T . P^T
        const u16* vbase = vt2 + (size_t)(h * 256 + kb * 4) * 512;
#if HAVE_MFMA16
#pragma unroll
        for (int kt = 0; kt < 4; ++kt) {
            s4v pb;
            pb[0] = (short)cvt1(st[kt][0]);
            pb[1] = (short)cvt1(st[kt][1]);
            pb[2] = (short)cvt1(st[kt][2]);
            pb[3] = (short)cvt1(st[kt][3]);
            const u16* vt = vbase + kt * 512;
            s4v v0 = *reinterpret_cast<const s4v*>(vt + lr * 16 + lg * 4);
            s4v v1 = *reinterpret_cast<const s4v*>(vt + (16 + lr) * 16 + lg * 4);
            o0 = MFMA16(v0, pb, o0);
            o1 = MFMA16(v1, pb, o1);
        }
#else
        // fallback: assemble 16x16x32 B-frags via shuffles
        u32 pk0[4], pk1[4];
#pragma unroll
        for (int kt = 0; kt < 4; ++kt) {
            pk0[kt] = bfpair(st[kt][0], st[kt][1]);
            pk1[kt] = bfpair(st[kt][2], st[kt][3]);
        }
        int srcbase = ((lg & 1) * 2) * 16 + lr;
        bool hiQuad = (lg >> 1) != 0;
#pragma unroll
        for (int s = 0; s < 2; ++s) {
            union { u32 u[4]; s8 v; } bu;
#pragma unroll
            for (int wi = 0; wi < 4; ++wi) {
                int src = srcbase + ((wi >> 1) << 4);
                u32 a0 = (u32)__shfl((int)((wi & 1) ? pk1[2 * s] : pk0[2 * s]), src);
                u32 a1 = (u32)__shfl((int)((wi & 1) ? pk1[2 * s + 1] : pk0[2 * s + 1]), src);
                bu.u[wi] = hiQuad ? a1 : a0;
            }
            int t = 2 * s + (lg >> 1);
            const u16* vt = vbase + t * 512 + (lg & 1) * 8;
            s8 v0 = ld8(vt + lr * 16);
            s8 v1 = ld8(vt + (16 + lr) * 16);
            o0 = MFMA32(v0, bu.v, o0);
            o1 = MFMA32(v1, bu.v, o1);
        }
#endif
    }

    // deposit per-wave partials
    float* c = cmb[w][l];
    c[0] = m; c[1] = sum;
#pragma unroll
    for (int r = 0; r < 4; ++r) { c[2 + r] = o0[r]; c[6 + r] = o1[r]; }
    __syncthreads();

    if (w == 0) {
        float M = cmb[0][l][0];
#pragma unroll
        for (int ww = 1; ww < KSPLIT; ++ww) M = fmaxf(M, cmb[ww][l][0]);
        float S = 0.0f;
        f4 O0 = {}, O1 = {};
#pragma unroll
        for (int ww = 0; ww < KSPLIT; ++ww) {
            const float* cc = cmb[ww][l];
            float fac = EXP2(cc[0] - M);
            S += fac * cc[1];
#pragma unroll
            for (int r = 0; r < 4; ++r) {
                O0[r] += fac * cc[2 + r];
                O1[r] += fac * cc[6 + r];
            }
        }
        float inv = 1.0f / (S + 1e-6f);
        int n = qb * 16 + lr;
        u16* dst0 = catH + n * 256 + h * HD + lg * 4;
        u32 w0 = bfpair(O0[0] * inv, O0[1] * inv);
        u32 w1 = bfpair(O0[2] * inv, O0[3] * inv);
        *reinterpret_cast<uint2*>(dst0) = make_uint2(w0, w1);
        u16* dst1 = dst0 + 16;
        u32 w2 = bfpair(O1[0] * inv, O1[1] * inv);
        u32 w3 = bfpair(O1[2] * inv, O1[3] * inv);
        *reinterpret_cast<uint2*>(dst1) = make_uint2(w2, w3);
    }
}

// ---------------------------------------------------------------------------
// Phase 4: out = cat @ wo + bo + x   (bf16 MFMA, fp32 epilogue)
// ---------------------------------------------------------------------------
__global__ __launch_bounds__(256) void k_out(
        const u16* __restrict__ catH, const u16* __restrict__ woT,
        const float* __restrict__ bo, const float* __restrict__ x,
        float* __restrict__ out) {
    int w = threadIdx.x >> 6, l = threadIdx.x & 63;
    int lr = l & 15, lg = l >> 4;
    int r0 = blockIdx.x * 64 + w * 16;
    int c0 = blockIdx.y * 64;
    f4 acc[4] = {};
#pragma unroll
    for (int kk = 0; kk < 8; ++kk) {
        s8 a = ld8(catH + (r0 + lr) * 256 + kk * 32 + lg * 8);
#pragma unroll
        for (int ct = 0; ct < 4; ++ct) {
            s8 b = ld8(woT + (c0 + ct * 16 + lr) * 256 + kk * 32 + lg * 8);
            acc[ct] = MFMA32(a, b, acc[ct]);
        }
    }
#pragma unroll
    for (int ct = 0; ct < 4; ++ct) {
        int c = c0 + ct * 16 + lr;
        float bias = bo[c];
#pragma unroll
        for (int r = 0; r < 4; ++r) {
            int n = r0 + lg * 4 + r;
            out[n * 256 + c] = acc[ct][r] + bias + x[n * 256 + c];
        }
    }
}

// ---------------------------------------------------------------------------
extern "C" void kernel_launch(void* const* d_in, const int* in_sizes, int n_in,
                              void* d_out, int out_size, void* d_ws, size_t ws_size,
                              hipStream_t stream) {
    const float* x      = (const float*)d_in[0];
    const int*   coords = (const int*)d_in[1];
    const float* wq     = (const float*)d_in[2];
    const float* bq     = (const float*)d_in[3];
    const float* wk     = (const float*)d_in[4];
    const float* bk     = (const float*)d_in[5];
    const float* wv     = (const float*)d_in[6];
    const float* bv     = (const float*)d_in[7];
    const float* wo     = (const float*)d_in[8];
    const float* bo     = (const float*)d_in[9];
    float* out = (float*)d_out;

    char* ws = (char*)d_ws;
    size_t off = 0;
    auto alloc = [&](size_t bytes) {
        char* p = ws + off;
        off = (off + bytes + 255) & ~(size_t)255;
        return p;
    };
    u16* xcHi = (u16*)alloc((size_t)NPTS * DINP * 2);
    u16* xcLo = (u16*)alloc((size_t)NPTS * DINP * 2);
    u16* wtHi = (u16*)alloc((size_t)COUT * DINP * 2);
    u16* wtLo = (u16*)alloc((size_t)COUT * DINP * 2);
    u16* qHi  = (u16*)alloc((size_t)NH * NPTS * HD * 2);
    u16* qLo  = (u16*)alloc((size_t)NH * NPTS * HD * 2);
    u16* kHi  = (u16*)alloc((size_t)NH * NPTS * HD * 2);
    u16* kLo  = (u16*)alloc((size_t)NH * NPTS * HD * 2);
    u16* vt2  = (u16*)alloc((size_t)NH * NPTS * HD * 2);
    u16* catH = (u16*)alloc((size_t)NPTS * 256 * 2);
    u16* woT  = (u16*)alloc((size_t)256 * 256 * 2);
    (void)ws_size; (void)in_sizes; (void)n_in; (void)out_size;

    k_wprep<<<COUT, 64, 0, stream>>>(wq, wk, wv, wtHi, wtLo);
    k_woprep<<<256, 256, 0, stream>>>(wo, woT);
    k_featurize<<<NPTS, 64, 0, stream>>>(x, coords, xcHi, xcLo);
    k_qkv<<<dim3(NPTS / 64, COUT / 64), 256, 0, stream>>>(
        xcHi, xcLo, wtHi, wtLo, bq, bk, bv, qHi, qLo, kHi, kLo, vt2);
    k_attn<<<NPTS / 16 * NH, 256, 0, stream>>>(qHi, qLo, kHi, kLo, vt2, catH);
    k_out<<<dim3(NPTS / 64, 256 / 64), 256, 0, stream>>>(catH, woT, bo, x, out);
}

// Round 6
// 149.253 us; speedup vs baseline: 1.1085x; 1.1085x over previous
//
#include <hip/hip_runtime.h>
#include <hip/hip_bf16.h>

// ---------------------------------------------------------------------------
// MultiHeadAttention: feats L2-norm + clamp(coords) concat -> per-head QKV
// (DIN=259, HD=32, H=8) -> softmax attention (N=4096, clip +-100, /(sum+1e-6))
// -> output proj + bias + residual.
// Precision: hi/lo bf16 split (3-MFMA fp32 emulation) for QKV proj and QK^T;
// bf16 P and bf16 V for PV; plain bf16 for output proj.
// Attention: swapped-operand QK^T (S^T = K.Q^T) so softmax is lane-local,
// Q pre-scaled by scale*log2e (log2-domain scores), PV via 16x16x16 MFMA
// (B-frag == packed P), split-K 4 waves/block + LDS merge.
// P is packed to bf16 INSIDE the exp loop so st[] dies early -> live set
// ~56 VGPR -> launch_bounds(256,8) without spilling (round-5 lesson).
// ---------------------------------------------------------------------------

using s8  = __attribute__((ext_vector_type(8))) short;   // 8 x bf16 (4 VGPR)
using s4v = __attribute__((ext_vector_type(4))) short;   // 4 x bf16 (2 VGPR)
using f4  = __attribute__((ext_vector_type(4))) float;   // MFMA C/D
typedef unsigned short u16;
typedef unsigned int   u32;

#define NPTS 4096
#define NH   8
#define HD   32
#define DIN  259
#define DINP 288       // padded K-dim for QKV GEMM (9 x 32)
#define COUT 768       // 3*NH*HD, col c = s*256 + h*32 + hd (s: 0=q,1=k,2=v)
#define KBLK 64        // attention keys per inner iteration (VGPR budget)
#define KSPLIT 4       // waves per block, each takes NPTS/KSPLIT keys

// scale * log2(e): QK^T in log2 domain (monotone, identical softmax)
#define SCL2  (0.17677669529663687f * 1.4426950408889634f)
#define CLIP2 (100.0f * 1.4426950408889634f)

#define MFMA32(a, b, c) __builtin_amdgcn_mfma_f32_16x16x32_bf16((a), (b), (c), 0, 0, 0)

#if __has_builtin(__builtin_amdgcn_mfma_f32_16x16x16bf16_1k)
#define HAVE_MFMA16 1
#define MFMA16(a, b, c) __builtin_amdgcn_mfma_f32_16x16x16bf16_1k((a), (b), (c), 0, 0, 0)
#else
#define HAVE_MFMA16 0
#endif

#if __has_builtin(__builtin_amdgcn_exp2f)
#define EXP2(x) __builtin_amdgcn_exp2f(x)
#else
#define EXP2(x) exp2f(x)
#endif

__device__ __forceinline__ u16 f2bf(float f) {           // RNE, for cold paths
    u32 u = __float_as_uint(f);
    u32 r = u + 0x7FFFu + ((u >> 16) & 1u);
    return (u16)(r >> 16);
}
__device__ __forceinline__ float bf2f(u16 h) { return __uint_as_float(((u32)h) << 16); }
__device__ __forceinline__ void splitbf(float v, u16& hi, u16& lo) {
    hi = f2bf(v);
    lo = f2bf(v - bf2f(hi));
}
__device__ __forceinline__ u16 cvt1(float f) {           // native convert (RNE)
    __hip_bfloat16 b = __float2bfloat16(f);
    return *reinterpret_cast<u16*>(&b);
}
__device__ __forceinline__ s8 ld8(const u16* p) { return *reinterpret_cast<const s8*>(p); }
__device__ __forceinline__ u32 bfpair(float a, float b) {
    return (u32)cvt1(a) | ((u32)cvt1(b) << 16);
}

// ---------------------------------------------------------------------------
// Phase 0a: build transposed+split QKV weight matrix Wt[COUT][DINP]
// ---------------------------------------------------------------------------
__global__ void k_wprep(const float* __restrict__ wq, const float* __restrict__ wk,
                        const float* __restrict__ wv,
                        u16* __restrict__ wtHi, u16* __restrict__ wtLo) {
    int c = blockIdx.x;                   // 0..767
    int s = c >> 8, h = (c >> 5) & 7, hd = c & 31;
    const float* w = (s == 0) ? wq : (s == 1) ? wk : wv;
    for (int k = threadIdx.x; k < DINP; k += blockDim.x) {
        float val = (k < DIN) ? w[(h * DIN + k) * HD + hd] : 0.0f;
        u16 hi, lo; splitbf(val, hi, lo);
        wtHi[c * DINP + k] = hi;
        wtLo[c * DINP + k] = lo;
    }
}

// ---------------------------------------------------------------------------
// Phase 0b: woT[c][k] = wo[k][c] (bf16)
// ---------------------------------------------------------------------------
__global__ void k_woprep(const float* __restrict__ wo, u16* __restrict__ woT) {
    int c = blockIdx.x;
    int k = threadIdx.x;                  // blockDim = 256
    woT[c * 256 + k] = f2bf(wo[k * 256 + c]);
}

// ---------------------------------------------------------------------------
// Phase 1: featurize. One 64-lane wave per row.
// ---------------------------------------------------------------------------
__global__ __launch_bounds__(64) void k_featurize(const float* __restrict__ x,
                                                  const int* __restrict__ coords,
                                                  u16* __restrict__ xcHi,
                                                  u16* __restrict__ xcLo) {
    int row = blockIdx.x;
    int l = threadIdx.x;
    f4 v = *reinterpret_cast<const f4*>(x + row * 256 + 4 * l);
    float ss = v[0] * v[0] + v[1] * v[1] + v[2] * v[2] + v[3] * v[3];
#pragma unroll
    for (int m = 1; m < 64; m <<= 1) ss += __shfl_xor(ss, m);
    float inv = 1.0f / (sqrtf(ss) + 1e-6f);
#pragma unroll
    for (int j = 0; j < 4; ++j) {
        u16 hi, lo; splitbf(v[j] * inv, hi, lo);
        xcHi[row * DINP + 4 * l + j] = hi;
        xcLo[row * DINP + 4 * l + j] = lo;
    }
    if (l < 32) {
        int col = 256 + l;
        float val = 0.0f;
        if (col < DIN) {
            float c = (float)coords[row * 3 + (col - 256)];
            val = fminf(fmaxf(c, -100.0f), 100.0f);
        }
        u16 hi, lo; splitbf(val, hi, lo);
        xcHi[row * DINP + col] = hi;
        xcLo[row * DINP + col] = lo;
    }
}

// ---------------------------------------------------------------------------
// Phase 2: QKV GEMM  [4096 x DINP] x [DINP x 768] with 3-MFMA emulation.
// q (pre-scaled by SCL2), k row-major [h][n][hd] (hi/lo);
// v tiled [h][n>>4][hd][n&15] (bf16).
// ---------------------------------------------------------------------------
__global__ __launch_bounds__(256) void k_qkv(
        const u16* __restrict__ xcHi, const u16* __restrict__ xcLo,
        const u16* __restrict__ wtHi, const u16* __restrict__ wtLo,
        const float* __restrict__ bq, const float* __restrict__ bk,
        const float* __restrict__ bv,
        u16* __restrict__ qHi, u16* __restrict__ qLo,
        u16* __restrict__ kHi, u16* __restrict__ kLo,
        u16* __restrict__ vt2) {
    int w = threadIdx.x >> 6, l = threadIdx.x & 63;
    int lr = l & 15, lg = l >> 4;
    int r0 = blockIdx.x * 64 + w * 16;    // wave's row base
    int c0 = blockIdx.y * 64;             // block's col base

    f4 acc[4] = {};
    const u16* aH = xcHi + (r0 + lr) * DINP + lg * 8;
    const u16* aL = xcLo + (r0 + lr) * DINP + lg * 8;
#pragma unroll
    for (int kk = 0; kk < 9; ++kk) {
        s8 ah = ld8(aH + kk * 32);
        s8 al = ld8(aL + kk * 32);
#pragma unroll
        for (int ct = 0; ct < 4; ++ct) {
            int c = c0 + ct * 16 + lr;
            s8 bh = ld8(wtHi + c * DINP + kk * 32 + lg * 8);
            s8 bl = ld8(wtLo + c * DINP + kk * 32 + lg * 8);
            acc[ct] = MFMA32(al, bh, acc[ct]);
            acc[ct] = MFMA32(ah, bl, acc[ct]);
            acc[ct] = MFMA32(ah, bh, acc[ct]);
        }
    }
#pragma unroll
    for (int ct = 0; ct < 4; ++ct) {
        int c = c0 + ct * 16 + lr;
        int s = c >> 8, h = (c >> 5) & 7, hd = c & 31;
        float bias = ((s == 0) ? bq : (s == 1) ? bk : bv)[h * HD + hd];
#pragma unroll
        for (int r = 0; r < 4; ++r) {
            int n = r0 + lg * 4 + r;
            float val = acc[ct][r] + bias;
            if (s == 0) {
                u16 hi, lo; splitbf(val * SCL2, hi, lo);   // pre-scaled Q
                qHi[(h * NPTS + n) * HD + hd] = hi;
                qLo[(h * NPTS + n) * HD + hd] = lo;
            } else if (s == 1) {
                u16 hi, lo; splitbf(val, hi, lo);
                kHi[(h * NPTS + n) * HD + hd] = hi;
                kLo[(h * NPTS + n) * HD + hd] = lo;
            } else {
                // tiled V^T: [h][key tile][hd][key%16]
                vt2[((size_t)(h * 256 + (n >> 4)) * 32 + hd) * 16 + (n & 15)] = f2bf(val);
            }
        }
    }
}

// ---------------------------------------------------------------------------
// Phase 3: attention, split-K flash-decoding. Block = 4 waves on one
// (head, 16 q-rows); wave w handles keys [w*1024, w*1024+1024) in 16 iters
// of 64 keys. Swapped QK^T (log2-domain scores), lane-local softmax, P
// packed to bf16 in the exp loop (st dies early; ~56 live VGPR), PV via
// 16x16x16 MFMA. LDS merge of {m, sum, O}; wave 0 writes.
// blockIdx&7 = head -> per-XCD L2 holds one head's K/V.
// ---------------------------------------------------------------------------
__global__ __launch_bounds__(256, 8) void k_attn(
        const u16* __restrict__ qHi, const u16* __restrict__ qLo,
        const u16* __restrict__ kHi, const u16* __restrict__ kLo,
        const u16* __restrict__ vt2,
        u16* __restrict__ catH) {
    __shared__ float cmb[KSPLIT][64][13];  // {m,sum,o0[4],o1[4]} stride 13
    int b = blockIdx.x;
    int h = b & 7;                        // head -> XCD affinity
    int qb = b >> 3;                      // 0..255
    int w = threadIdx.x >> 6;             // key-split index
    int l = threadIdx.x & 63, lr = l & 15, lg = l >> 4;

    size_t qoff = (size_t)(h * NPTS + qb * 16 + lr) * HD + lg * 8;
    s8 qh = ld8(qHi + qoff);
    s8 ql = ld8(qLo + qoff);

    float m = -1.0e30f, sum = 0.0f;
    f4 o0 = {}, o1 = {};

#pragma unroll 1
    for (int kb = w * (NPTS / KSPLIT / KBLK); kb < (w + 1) * (NPTS / KSPLIT / KBLK); ++kb) {
        int kr0 = kb * KBLK;
        // S^T tiles: st[kt] holds S^T[key = kt*16 + lg*4 + r][q = lr], log2 domain
        f4 st[4];
#pragma unroll
        for (int kt = 0; kt < 4; ++kt) {
            size_t koff = (size_t)(h * NPTS + kr0 + kt * 16 + lr) * HD + lg * 8;
            s8 kh = ld8(kHi + koff);
            s8 kl = ld8(kLo + koff);
            f4 a = {};
            a = MFMA32(kl, qh, a);
            a = MFMA32(kh, ql, a);
            a = MFMA32(kh, qh, a);
            st[kt] = a;
        }
        // upper clip only (lower clip provably inert for softmax output)
#pragma unroll
        for (int kt = 0; kt < 4; ++kt)
#pragma unroll
            for (int r = 0; r < 4; ++r) st[kt][r] = fminf(st[kt][r], CLIP2);
        // row max: in-lane tree over 16 keys + butterfly across 4 lane groups
        float t0 = fmaxf(fmaxf(st[0][0], st[0][1]), fmaxf(st[0][2], st[0][3]));
        float t1 = fmaxf(fmaxf(st[1][0], st[1][1]), fmaxf(st[1][2], st[1][3]));
        float t2 = fmaxf(fmaxf(st[2][0], st[2][1]), fmaxf(st[2][2], st[2][3]));
        float t3 = fmaxf(fmaxf(st[3][0], st[3][1]), fmaxf(st[3][2], st[3][3]));
        float tm = fmaxf(fmaxf(t0, t1), fmaxf(t2, t3));
        tm = fmaxf(tm, __shfl_xor(tm, 16));
        tm = fmaxf(tm, __shfl_xor(tm, 32));
        float mn = fmaxf(m, tm);
        float fac = EXP2(m - mn);
        m = mn;
        sum *= fac;
#pragma unroll
        for (int r = 0; r < 4; ++r) { o0[r] *= fac; o1[r] *= fac; }
        // p = 2^(s-m): sum partials AND pack to bf16 immediately (st dies here)
        u32 pkA[4], pkB[4];
        float ps0 = 0.0f, ps1 = 0.0f, ps2 = 0.0f, ps3 = 0.0f;
#pragma unroll
        for (int kt = 0; kt < 4; ++kt) {
            float p0 = EXP2(st[kt][0] - m); ps0 += p0;
            float p1 = EXP2(st[kt][1] - m); ps1 += p1;
            float p2 = EXP2(st[kt][2] - m); ps2 += p2;
            float p3 = EXP2(st[kt][3] - m); ps3 += p3;
            pkA[kt] = bfpair(p0, p1);
            pkB[kt] = bfpair(p2, p3);
        }
        float ps = (ps0 + ps1) + (ps2 + ps3);
        ps += __shfl_xor(ps, 16);
        ps += __shfl_xor(ps, 32);
        sum += ps;

        // PV: O^T += V^T . P^T
        const u16* vbase = vt2 + (size_t)(h * 256 + kb * 4) * 512;
#if HAVE_MFMA16
#pragma unroll
        for (int kt = 0; kt < 4; ++kt) {
            union { u32 u[2]; s4v v; } pu;
            pu.u[0] = pkA[kt];
            pu.u[1] = pkB[kt];
            const u16* vt = vbase + kt * 512;
            s4v v0 = *reinterpret_cast<const s4v*>(vt + lr * 16 + lg * 4);
            s4v v1 = *reinterpret_cast<const s4v*>(vt + (16 + lr) * 16 + lg * 4);
            o0 = MFMA16(v0, pu.v, o0);
            o1 = MFMA16(v1, pu.v, o1);
        }
#else
        // fallback: assemble 16x16x32 B-frags via shuffles
        int srcbase = ((lg & 1) * 2) * 16 + lr;
        bool hiQuad = (lg >> 1) != 0;
#pragma unroll
        for (int s = 0; s < 2; ++s) {
            union { u32 u[4]; s8 v; } bu;
#pragma unroll
            for (int wi = 0; wi < 4; ++wi) {
                int src = srcbase + ((wi >> 1) << 4);
                u32 a0 = (u32)__shfl((int)((wi & 1) ? pkB[2 * s] : pkA[2 * s]), src);
                u32 a1 = (u32)__shfl((int)((wi & 1) ? pkB[2 * s + 1] : pkA[2 * s + 1]), src);
                bu.u[wi] = hiQuad ? a1 : a0;
            }
            int t = 2 * s + (lg >> 1);
            const u16* vt = vbase + t * 512 + (lg & 1) * 8;
            s8 v0 = ld8(vt + lr * 16);
            s8 v1 = ld8(vt + (16 + lr) * 16);
            o0 = MFMA32(v0, bu.v, o0);
            o1 = MFMA32(v1, bu.v, o1);
        }
#endif
    }

    // deposit per-wave partials
    float* c = cmb[w][l];
    c[0] = m; c[1] = sum;
#pragma unroll
    for (int r = 0; r < 4; ++r) { c[2 + r] = o0[r]; c[6 + r] = o1[r]; }
    __syncthreads();

    if (w == 0) {
        float M = cmb[0][l][0];
#pragma unroll
        for (int ww = 1; ww < KSPLIT; ++ww) M = fmaxf(M, cmb[ww][l][0]);
        float S = 0.0f;
        f4 O0 = {}, O1 = {};
#pragma unroll
        for (int ww = 0; ww < KSPLIT; ++ww) {
            const float* cc = cmb[ww][l];
            float fac = EXP2(cc[0] - M);
            S += fac * cc[1];
#pragma unroll
            for (int r = 0; r < 4; ++r) {
                O0[r] += fac * cc[2 + r];
                O1[r] += fac * cc[6 + r];
            }
        }
        float inv = 1.0f / (S + 1e-6f);
        int n = qb * 16 + lr;
        u16* dst0 = catH + n * 256 + h * HD + lg * 4;
        u32 w0 = bfpair(O0[0] * inv, O0[1] * inv);
        u32 w1 = bfpair(O0[2] * inv, O0[3] * inv);
        *reinterpret_cast<uint2*>(dst0) = make_uint2(w0, w1);
        u16* dst1 = dst0 + 16;
        u32 w2 = bfpair(O1[0] * inv, O1[1] * inv);
        u32 w3 = bfpair(O1[2] * inv, O1[3] * inv);
        *reinterpret_cast<uint2*>(dst1) = make_uint2(w2, w3);
    }
}

// ---------------------------------------------------------------------------
// Phase 4: out = cat @ wo + bo + x   (bf16 MFMA, fp32 epilogue)
// ---------------------------------------------------------------------------
__global__ __launch_bounds__(256) void k_out(
        const u16* __restrict__ catH, const u16* __restrict__ woT,
        const float* __restrict__ bo, const float* __restrict__ x,
        float* __restrict__ out) {
    int w = threadIdx.x >> 6, l = threadIdx.x & 63;
    int lr = l & 15, lg = l >> 4;
    int r0 = blockIdx.x * 64 + w * 16;
    int c0 = blockIdx.y * 64;
    f4 acc[4] = {};
#pragma unroll
    for (int kk = 0; kk < 8; ++kk) {
        s8 a = ld8(catH + (r0 + lr) * 256 + kk * 32 + lg * 8);
#pragma unroll
        for (int ct = 0; ct < 4; ++ct) {
            s8 b = ld8(woT + (c0 + ct * 16 + lr) * 256 + kk * 32 + lg * 8);
            acc[ct] = MFMA32(a, b, acc[ct]);
        }
    }
#pragma unroll
    for (int ct = 0; ct < 4; ++ct) {
        int c = c0 + ct * 16 + lr;
        float bias = bo[c];
#pragma unroll
        for (int r = 0; r < 4; ++r) {
            int n = r0 + lg * 4 + r;
            out[n * 256 + c] = acc[ct][r] + bias + x[n * 256 + c];
        }
    }
}

// ---------------------------------------------------------------------------
extern "C" void kernel_launch(void* const* d_in, const int* in_sizes, int n_in,
                              void* d_out, int out_size, void* d_ws, size_t ws_size,
                              hipStream_t stream) {
    const float* x      = (const float*)d_in[0];
    const int*   coords = (const int*)d_in[1];
    const float* wq     = (const float*)d_in[2];
    const float* bq     = (const float*)d_in[3];
    const float* wk     = (const float*)d_in[4];
    const float* bk     = (const float*)d_in[5];
    const float* wv     = (const float*)d_in[6];
    const float* bv     = (const float*)d_in[7];
    const float* wo     = (const float*)d_in[8];
    const float* bo     = (const float*)d_in[9];
    float* out = (float*)d_out;

    char* ws = (char*)d_ws;
    size_t off = 0;
    auto alloc = [&](size_t bytes) {
        char* p = ws + off;
        off = (off + bytes + 255) & ~(size_t)255;
        return p;
    };
    u16* xcHi = (u16*)alloc((size_t)NPTS * DINP * 2);
    u16* xcLo = (u16*)alloc((size_t)NPTS * DINP * 2);
    u16* wtHi = (u16*)alloc((size_t)COUT * DINP * 2);
    u16* wtLo = (u16*)alloc((size_t)COUT * DINP * 2);
    u16* qHi  = (u16*)alloc((size_t)NH * NPTS * HD * 2);
    u16* qLo  = (u16*)alloc((size_t)NH * NPTS * HD * 2);
    u16* kHi  = (u16*)alloc((size_t)NH * NPTS * HD * 2);
    u16* kLo  = (u16*)alloc((size_t)NH * NPTS * HD * 2);
    u16* vt2  = (u16*)alloc((size_t)NH * NPTS * HD * 2);
    u16* catH = (u16*)alloc((size_t)NPTS * 256 * 2);
    u16* woT  = (u16*)alloc((size_t)256 * 256 * 2);
    (void)ws_size; (void)in_sizes; (void)n_in; (void)out_size;

    k_wprep<<<COUT, 64, 0, stream>>>(wq, wk, wv, wtHi, wtLo);
    k_woprep<<<256, 256, 0, stream>>>(wo, woT);
    k_featurize<<<NPTS, 64, 0, stream>>>(x, coords, xcHi, xcLo);
    k_qkv<<<dim3(NPTS / 64, COUT / 64), 256, 0, stream>>>(
        xcHi, xcLo, wtHi, wtLo, bq, bk, bv, qHi, qLo, kHi, kLo, vt2);
    k_attn<<<NPTS / 16 * NH, 256, 0, stream>>>(qHi, qLo, kHi, kLo, vt2, catH);
    k_out<<<dim3(NPTS / 64, 256 / 64), 256, 0, stream>>>(catH, woT, bo, x, out);
}

// Round 7
// 132.814 us; speedup vs baseline: 1.2457x; 1.1238x over previous
//
#include <hip/hip_runtime.h>
#include <hip/hip_bf16.h>

// ---------------------------------------------------------------------------
// MultiHeadAttention: feats L2-norm + clamp(coords) concat -> per-head QKV
// (DIN=259, HD=32, H=8) -> softmax attention (N=4096, clip +-100, /(sum+1e-6))
// -> output proj + bias + residual.
// Precision: hi/lo bf16 split (3-MFMA fp32 emulation) for QKV proj and QK^T;
// bf16 P and bf16 V for PV; plain bf16 for output proj.
// Attention: swapped-operand QK^T (S^T = K.Q^T, log2-domain via pre-scaled Q),
// FIXED-SCALE softmax p' = 2^(s-64) (clip at +144.3 bounds p' <= 2^80, sums
// <= ~2^96 -- inside fp32/bf16 range), so there is NO online max/rescale and
// NO per-iteration cross-lane ops: iterations are independent streams into
// {S', O'} accumulators. Split-K 4 waves/block + trivial LDS sum-combine.
// launch_bounds(256,4): <=128 VGPR, no spill (rounds 5/6 lesson).
// ---------------------------------------------------------------------------

using s8  = __attribute__((ext_vector_type(8))) short;   // 8 x bf16 (4 VGPR)
using s4v = __attribute__((ext_vector_type(4))) short;   // 4 x bf16 (2 VGPR)
using f4  = __attribute__((ext_vector_type(4))) float;   // MFMA C/D
typedef unsigned short u16;
typedef unsigned int   u32;

#define NPTS 4096
#define NH   8
#define HD   32
#define DIN  259
#define DINP 288       // padded K-dim for QKV GEMM (9 x 32)
#define COUT 768       // 3*NH*HD, col c = s*256 + h*32 + hd (s: 0=q,1=k,2=v)
#define KBLK 64        // attention keys per inner iteration
#define KSPLIT 4       // waves per block, each takes NPTS/KSPLIT keys

// scale * log2(e): QK^T in log2 domain (monotone, identical softmax)
#define SCL2  (0.17677669529663687f * 1.4426950408889634f)
#define CLIP2 (100.0f * 1.4426950408889634f)
#define PRESC 64.0f    // fixed softmax prescale: p' = 2^(s - 64)

#define MFMA32(a, b, c) __builtin_amdgcn_mfma_f32_16x16x32_bf16((a), (b), (c), 0, 0, 0)

#if __has_builtin(__builtin_amdgcn_mfma_f32_16x16x16bf16_1k)
#define HAVE_MFMA16 1
#define MFMA16(a, b, c) __builtin_amdgcn_mfma_f32_16x16x16bf16_1k((a), (b), (c), 0, 0, 0)
#else
#define HAVE_MFMA16 0
#endif

#if __has_builtin(__builtin_amdgcn_exp2f)
#define EXP2(x) __builtin_amdgcn_exp2f(x)
#else
#define EXP2(x) exp2f(x)
#endif

__device__ __forceinline__ u16 f2bf(float f) {           // RNE, for cold paths
    u32 u = __float_as_uint(f);
    u32 r = u + 0x7FFFu + ((u >> 16) & 1u);
    return (u16)(r >> 16);
}
__device__ __forceinline__ float bf2f(u16 h) { return __uint_as_float(((u32)h) << 16); }
__device__ __forceinline__ void splitbf(float v, u16& hi, u16& lo) {
    hi = f2bf(v);
    lo = f2bf(v - bf2f(hi));
}
__device__ __forceinline__ u16 cvt1(float f) {           // native convert (RNE)
    __hip_bfloat16 b = __float2bfloat16(f);
    return *reinterpret_cast<u16*>(&b);
}
__device__ __forceinline__ s8 ld8(const u16* p) { return *reinterpret_cast<const s8*>(p); }
__device__ __forceinline__ u32 bfpair(float a, float b) {
    return (u32)cvt1(a) | ((u32)cvt1(b) << 16);
}

// ---------------------------------------------------------------------------
// Phase 0a: build transposed+split QKV weight matrix Wt[COUT][DINP]
// ---------------------------------------------------------------------------
__global__ void k_wprep(const float* __restrict__ wq, const float* __restrict__ wk,
                        const float* __restrict__ wv,
                        u16* __restrict__ wtHi, u16* __restrict__ wtLo) {
    int c = blockIdx.x;                   // 0..767
    int s = c >> 8, h = (c >> 5) & 7, hd = c & 31;
    const float* w = (s == 0) ? wq : (s == 1) ? wk : wv;
    for (int k = threadIdx.x; k < DINP; k += blockDim.x) {
        float val = (k < DIN) ? w[(h * DIN + k) * HD + hd] : 0.0f;
        u16 hi, lo; splitbf(val, hi, lo);
        wtHi[c * DINP + k] = hi;
        wtLo[c * DINP + k] = lo;
    }
}

// ---------------------------------------------------------------------------
// Phase 0b: woT[c][k] = wo[k][c] (bf16)
// ---------------------------------------------------------------------------
__global__ void k_woprep(const float* __restrict__ wo, u16* __restrict__ woT) {
    int c = blockIdx.x;
    int k = threadIdx.x;                  // blockDim = 256
    woT[c * 256 + k] = f2bf(wo[k * 256 + c]);
}

// ---------------------------------------------------------------------------
// Phase 1: featurize. One 64-lane wave per row.
// ---------------------------------------------------------------------------
__global__ __launch_bounds__(64) void k_featurize(const float* __restrict__ x,
                                                  const int* __restrict__ coords,
                                                  u16* __restrict__ xcHi,
                                                  u16* __restrict__ xcLo) {
    int row = blockIdx.x;
    int l = threadIdx.x;
    f4 v = *reinterpret_cast<const f4*>(x + row * 256 + 4 * l);
    float ss = v[0] * v[0] + v[1] * v[1] + v[2] * v[2] + v[3] * v[3];
#pragma unroll
    for (int m = 1; m < 64; m <<= 1) ss += __shfl_xor(ss, m);
    float inv = 1.0f / (sqrtf(ss) + 1e-6f);
#pragma unroll
    for (int j = 0; j < 4; ++j) {
        u16 hi, lo; splitbf(v[j] * inv, hi, lo);
        xcHi[row * DINP + 4 * l + j] = hi;
        xcLo[row * DINP + 4 * l + j] = lo;
    }
    if (l < 32) {
        int col = 256 + l;
        float val = 0.0f;
        if (col < DIN) {
            float c = (float)coords[row * 3 + (col - 256)];
            val = fminf(fmaxf(c, -100.0f), 100.0f);
        }
        u16 hi, lo; splitbf(val, hi, lo);
        xcHi[row * DINP + col] = hi;
        xcLo[row * DINP + col] = lo;
    }
}

// ---------------------------------------------------------------------------
// Phase 2: QKV GEMM  [4096 x DINP] x [DINP x 768] with 3-MFMA emulation.
// q (pre-scaled by SCL2), k row-major [h][n][hd] (hi/lo);
// v tiled [h][n>>4][hd][n&15] (bf16).
// ---------------------------------------------------------------------------
__global__ __launch_bounds__(256) void k_qkv(
        const u16* __restrict__ xcHi, const u16* __restrict__ xcLo,
        const u16* __restrict__ wtHi, const u16* __restrict__ wtLo,
        const float* __restrict__ bq, const float* __restrict__ bk,
        const float* __restrict__ bv,
        u16* __restrict__ qHi, u16* __restrict__ qLo,
        u16* __restrict__ kHi, u16* __restrict__ kLo,
        u16* __restrict__ vt2) {
    int w = threadIdx.x >> 6, l = threadIdx.x & 63;
    int lr = l & 15, lg = l >> 4;
    int r0 = blockIdx.x * 64 + w * 16;    // wave's row base
    int c0 = blockIdx.y * 64;             // block's col base

    f4 acc[4] = {};
    const u16* aH = xcHi + (r0 + lr) * DINP + lg * 8;
    const u16* aL = xcLo + (r0 + lr) * DINP + lg * 8;
#pragma unroll
    for (int kk = 0; kk < 9; ++kk) {
        s8 ah = ld8(aH + kk * 32);
        s8 al = ld8(aL + kk * 32);
#pragma unroll
        for (int ct = 0; ct < 4; ++ct) {
            int c = c0 + ct * 16 + lr;
            s8 bh = ld8(wtHi + c * DINP + kk * 32 + lg * 8);
            s8 bl = ld8(wtLo + c * DINP + kk * 32 + lg * 8);
            acc[ct] = MFMA32(al, bh, acc[ct]);
            acc[ct] = MFMA32(ah, bl, acc[ct]);
            acc[ct] = MFMA32(ah, bh, acc[ct]);
        }
    }
#pragma unroll
    for (int ct = 0; ct < 4; ++ct) {
        int c = c0 + ct * 16 + lr;
        int s = c >> 8, h = (c >> 5) & 7, hd = c & 31;
        float bias = ((s == 0) ? bq : (s == 1) ? bk : bv)[h * HD + hd];
#pragma unroll
        for (int r = 0; r < 4; ++r) {
            int n = r0 + lg * 4 + r;
            float val = acc[ct][r] + bias;
            if (s == 0) {
                u16 hi, lo; splitbf(val * SCL2, hi, lo);   // pre-scaled Q
                qHi[(h * NPTS + n) * HD + hd] = hi;
                qLo[(h * NPTS + n) * HD + hd] = lo;
            } else if (s == 1) {
                u16 hi, lo; splitbf(val, hi, lo);
                kHi[(h * NPTS + n) * HD + hd] = hi;
                kLo[(h * NPTS + n) * HD + hd] = lo;
            } else {
                // tiled V^T: [h][key tile][hd][key%16]
                vt2[((size_t)(h * 256 + (n >> 4)) * 32 + hd) * 16 + (n & 15)] = f2bf(val);
            }
        }
    }
}

// ---------------------------------------------------------------------------
// Phase 3: attention, split-K flash-decoding with FIXED-SCALE softmax.
// Block = 4 waves on one (head, 16 q-rows); wave w handles keys
// [w*1024, (w+1)*1024) in 16 iters of 64 keys. No online max, no per-iter
// cross-lane ops: p' = 2^(s-64), accumulate S' and O' = sum p'.v directly.
// Epilogue: butterfly S' across lane groups, LDS sum-combine, O = O'/S'.
// blockIdx&7 = head -> per-XCD L2 holds one head's K/V.
// ---------------------------------------------------------------------------
__global__ __launch_bounds__(256, 4) void k_attn(
        const u16* __restrict__ qHi, const u16* __restrict__ qLo,
        const u16* __restrict__ kHi, const u16* __restrict__ kLo,
        const u16* __restrict__ vt2,
        u16* __restrict__ catH) {
    __shared__ float cmb[KSPLIT][64][13];  // {S', o0[4], o1[4]} stride 13
    int b = blockIdx.x;
    int h = b & 7;                        // head -> XCD affinity
    int qb = b >> 3;                      // 0..255
    int w = threadIdx.x >> 6;             // key-split index
    int l = threadIdx.x & 63, lr = l & 15, lg = l >> 4;

    size_t qoff = (size_t)(h * NPTS + qb * 16 + lr) * HD + lg * 8;
    s8 qh = ld8(qHi + qoff);
    s8 ql = ld8(qLo + qoff);

    // hoisted bases (32-bit per-iter offsets)
    const u16* khb = kHi + (size_t)h * NPTS * HD + lr * HD + lg * 8;
    const u16* klb = kLo + (size_t)h * NPTS * HD + lr * HD + lg * 8;
    const u16* vtb = vt2 + (size_t)h * (NPTS / 16) * 512 + lr * 16 + lg * 4;

    float ps0 = 0.0f, ps1 = 0.0f, ps2 = 0.0f, ps3 = 0.0f;
    f4 o0 = {}, o1 = {};

#pragma unroll 2
    for (int kb = w * (NPTS / KSPLIT / KBLK); kb < (w + 1) * (NPTS / KSPLIT / KBLK); ++kb) {
        // S^T tiles: st[kt] holds S^T[key = kt*16 + lg*4 + r][q = lr], log2 domain
        f4 st[4];
#pragma unroll
        for (int kt = 0; kt < 4; ++kt) {
            int koff = (kb * KBLK + kt * 16) * HD;
            s8 kh = ld8(khb + koff);
            s8 kl = ld8(klb + koff);
            f4 a = {};
            a = MFMA32(kl, qh, a);
            a = MFMA32(kh, ql, a);
            a = MFMA32(kh, qh, a);
            st[kt] = a;
        }
        // p' = 2^(min(s, CLIP2) - 64); accumulate partial sums; pack bf16
        u32 pkA[4], pkB[4];
#pragma unroll
        for (int kt = 0; kt < 4; ++kt) {
            float p0 = EXP2(fminf(st[kt][0] - PRESC, CLIP2 - PRESC)); ps0 += p0;
            float p1 = EXP2(fminf(st[kt][1] - PRESC, CLIP2 - PRESC)); ps1 += p1;
            float p2 = EXP2(fminf(st[kt][2] - PRESC, CLIP2 - PRESC)); ps2 += p2;
            float p3 = EXP2(fminf(st[kt][3] - PRESC, CLIP2 - PRESC)); ps3 += p3;
            pkA[kt] = bfpair(p0, p1);
            pkB[kt] = bfpair(p2, p3);
        }

        // PV: O'^T += V^T . P'^T
        int vo = kb * 2048;
#if HAVE_MFMA16
#pragma unroll
        for (int kt = 0; kt < 4; ++kt) {
            union { u32 u[2]; s4v v; } pu;
            pu.u[0] = pkA[kt];
            pu.u[1] = pkB[kt];
            s4v v0 = *reinterpret_cast<const s4v*>(vtb + vo + kt * 512);
            s4v v1 = *reinterpret_cast<const s4v*>(vtb + vo + kt * 512 + 256);
            o0 = MFMA16(v0, pu.v, o0);
            o1 = MFMA16(v1, pu.v, o1);
        }
#else
        // fallback: assemble 16x16x32 B-frags via shuffles
        int srcbase = ((lg & 1) * 2) * 16 + lr;
        bool hiQuad = (lg >> 1) != 0;
#pragma unroll
        for (int s = 0; s < 2; ++s) {
            union { u32 u[4]; s8 v; } bu;
#pragma unroll
            for (int wi = 0; wi < 4; ++wi) {
                int src = srcbase + ((wi >> 1) << 4);
                u32 a0 = (u32)__shfl((int)((wi & 1) ? pkB[2 * s] : pkA[2 * s]), src);
                u32 a1 = (u32)__shfl((int)((wi & 1) ? pkB[2 * s + 1] : pkA[2 * s + 1]), src);
                bu.u[wi] = hiQuad ? a1 : a0;
            }
            int t = 2 * s + (lg >> 1);
            const u16* vt = vtb - lr * 16 - lg * 4 + vo + t * 512 + (lg & 1) * 8;
            s8 v0 = ld8(vt + lr * 16);
            s8 v1 = ld8(vt + (16 + lr) * 16);
            o0 = MFMA32(v0, bu.v, o0);
            o1 = MFMA32(v1, bu.v, o1);
        }
#endif
    }

    // per-wave: reduce S' across the 4 lane groups (once, not per iter)
    float S = (ps0 + ps1) + (ps2 + ps3);
    S += __shfl_xor(S, 16);
    S += __shfl_xor(S, 32);

    // deposit per-wave partials (all share the fixed 2^-64 scale)
    float* c = cmb[w][l];
    c[0] = S;
#pragma unroll
    for (int r = 0; r < 4; ++r) { c[1 + r] = o0[r]; c[5 + r] = o1[r]; }
    __syncthreads();

    if (w == 0) {
        float St = 0.0f;
        f4 O0 = {}, O1 = {};
#pragma unroll
        for (int ww = 0; ww < KSPLIT; ++ww) {
            const float* cc = cmb[ww][l];
            St += cc[0];
#pragma unroll
            for (int r = 0; r < 4; ++r) {
                O0[r] += cc[1 + r];
                O1[r] += cc[5 + r];
            }
        }
        // reference's +1e-6 on the max-normalized sum perturbs output by
        // <=1e-6 relative -- negligible vs bf16 rounding; plain divide.
        float inv = 1.0f / St;
        int n = qb * 16 + lr;
        u16* dst0 = catH + n * 256 + h * HD + lg * 4;
        u32 w0 = bfpair(O0[0] * inv, O0[1] * inv);
        u32 w1 = bfpair(O0[2] * inv, O0[3] * inv);
        *reinterpret_cast<uint2*>(dst0) = make_uint2(w0, w1);
        u16* dst1 = dst0 + 16;
        u32 w2 = bfpair(O1[0] * inv, O1[1] * inv);
        u32 w3 = bfpair(O1[2] * inv, O1[3] * inv);
        *reinterpret_cast<uint2*>(dst1) = make_uint2(w2, w3);
    }
}

// ---------------------------------------------------------------------------
// Phase 4: out = cat @ wo + bo + x   (bf16 MFMA, fp32 epilogue)
// ---------------------------------------------------------------------------
__global__ __launch_bounds__(256) void k_out(
        const u16* __restrict__ catH, const u16* __restrict__ woT,
        const float* __restrict__ bo, const float* __restrict__ x,
        float* __restrict__ out) {
    int w = threadIdx.x >> 6, l = threadIdx.x & 63;
    int lr = l & 15, lg = l >> 4;
    int r0 = blockIdx.x * 64 + w * 16;
    int c0 = blockIdx.y * 64;
    f4 acc[4] = {};
#pragma unroll
    for (int kk = 0; kk < 8; ++kk) {
        s8 a = ld8(catH + (r0 + lr) * 256 + kk * 32 + lg * 8);
#pragma unroll
        for (int ct = 0; ct < 4; ++ct) {
            s8 b = ld8(woT + (c0 + ct * 16 + lr) * 256 + kk * 32 + lg * 8);
            acc[ct] = MFMA32(a, b, acc[ct]);
        }
    }
#pragma unroll
    for (int ct = 0; ct < 4; ++ct) {
        int c = c0 + ct * 16 + lr;
        float bias = bo[c];
#pragma unroll
        for (int r = 0; r < 4; ++r) {
            int n = r0 + lg * 4 + r;
            out[n * 256 + c] = acc[ct][r] + bias + x[n * 256 + c];
        }
    }
}

// ---------------------------------------------------------------------------
extern "C" void kernel_launch(void* const* d_in, const int* in_sizes, int n_in,
                              void* d_out, int out_size, void* d_ws, size_t ws_size,
                              hipStream_t stream) {
    const float* x      = (const float*)d_in[0];
    const int*   coords = (const int*)d_in[1];
    const float* wq     = (const float*)d_in[2];
    const float* bq     = (const float*)d_in[3];
    const float* wk     = (const float*)d_in[4];
    const float* bk     = (const float*)d_in[5];
    const float* wv     = (const float*)d_in[6];
    const float* bv     = (const float*)d_in[7];
    const float* wo     = (const float*)d_in[8];
    const float* bo     = (const float*)d_in[9];
    float* out = (float*)d_out;

    char* ws = (char*)d_ws;
    size_t off = 0;
    auto alloc = [&](size_t bytes) {
        char* p = ws + off;
        off = (off + bytes + 255) & ~(size_t)255;
        return p;
    };
    u16* xcHi = (u16*)alloc((size_t)NPTS * DINP * 2);
    u16* xcLo = (u16*)alloc((size_t)NPTS * DINP * 2);
    u16* wtHi = (u16*)alloc((size_t)COUT * DINP * 2);
    u16* wtLo = (u16*)alloc((size_t)COUT * DINP * 2);
    u16* qHi  = (u16*)alloc((size_t)NH * NPTS * HD * 2);
    u16* qLo  = (u16*)alloc((size_t)NH * NPTS * HD * 2);
    u16* kHi  = (u16*)alloc((size_t)NH * NPTS * HD * 2);
    u16* kLo  = (u16*)alloc((size_t)NH * NPTS * HD * 2);
    u16* vt2  = (u16*)alloc((size_t)NH * NPTS * HD * 2);
    u16* catH = (u16*)alloc((size_t)NPTS * 256 * 2);
    u16* woT  = (u16*)alloc((size_t)256 * 256 * 2);
    (void)ws_size; (void)in_sizes; (void)n_in; (void)out_size;

    k_wprep<<<COUT, 64, 0, stream>>>(wq, wk, wv, wtHi, wtLo);
    k_woprep<<<256, 256, 0, stream>>>(wo, woT);
    k_featurize<<<NPTS, 64, 0, stream>>>(x, coords, xcHi, xcLo);
    k_qkv<<<dim3(NPTS / 64, COUT / 64), 256, 0, stream>>>(
        xcHi, xcLo, wtHi, wtLo, bq, bk, bv, qHi, qLo, kHi, kLo, vt2);
    k_attn<<<NPTS / 16 * NH, 256, 0, stream>>>(qHi, qLo, kHi, kLo, vt2, catH);
    k_out<<<dim3(NPTS / 64, 256 / 64), 256, 0, stream>>>(catH, woT, bo, x, out);
}

// Round 8
// 92.863 us; speedup vs baseline: 1.7817x; 1.4302x over previous
//
#include <hip/hip_runtime.h>
#include <hip/hip_bf16.h>

// ---------------------------------------------------------------------------
// MultiHeadAttention: feats L2-norm + clamp(coords) concat -> per-head QKV
// (DIN=259, HD=32, H=8) -> softmax attention (N=4096, clip +-100, /(sum+1e-6))
// -> output proj + bias + residual.
// Precision: hi/lo bf16 split (3-MFMA fp32 emulation) for QKV proj and QK^T;
// bf16 P and bf16 V for PV; plain bf16 for output proj.
// Attention: swapped-operand QK^T (S^T = K.Q^T, log2 domain via pre-scaled Q),
// FIXED-SCALE softmax p' = 2^(s-64) (no online max, no per-iter cross-lane
// ops), split-K 4 waves/block, and a 32-ROW Q-TILE per block: two 16-row
// score tiles share every K and V fragment -> halves L2 traffic (the round-7
// bottleneck: 1.57 GB L2 reads ~ 2.2x per-XCD L2 floor) and doubles ILP.
// launch_bounds(256,4): <=128 VGPR, no spill (rounds 5/6 lesson).
// ---------------------------------------------------------------------------

using s8  = __attribute__((ext_vector_type(8))) short;   // 8 x bf16 (4 VGPR)
using s4v = __attribute__((ext_vector_type(4))) short;   // 4 x bf16 (2 VGPR)
using f4  = __attribute__((ext_vector_type(4))) float;   // MFMA C/D
typedef unsigned short u16;
typedef unsigned int   u32;

#define NPTS 4096
#define NH   8
#define HD   32
#define DIN  259
#define DINP 288       // padded K-dim for QKV GEMM (9 x 32)
#define COUT 768       // 3*NH*HD, col c = s*256 + h*32 + hd (s: 0=q,1=k,2=v)
#define KBLK 64        // attention keys per inner iteration
#define KSPLIT 4       // waves per block, each takes NPTS/KSPLIT keys
#define QROWS 32       // q-rows per block (two 16-row MFMA tiles)

// scale * log2(e): QK^T in log2 domain (monotone, identical softmax)
#define SCL2  (0.17677669529663687f * 1.4426950408889634f)
#define CLIP2 (100.0f * 1.4426950408889634f)
#define PRESC 64.0f    // fixed softmax prescale: p' = 2^(s - 64)

#define MFMA32(a, b, c) __builtin_amdgcn_mfma_f32_16x16x32_bf16((a), (b), (c), 0, 0, 0)

#if __has_builtin(__builtin_amdgcn_mfma_f32_16x16x16bf16_1k)
#define HAVE_MFMA16 1
#define MFMA16(a, b, c) __builtin_amdgcn_mfma_f32_16x16x16bf16_1k((a), (b), (c), 0, 0, 0)
#else
#define HAVE_MFMA16 0
#endif

#if __has_builtin(__builtin_amdgcn_exp2f)
#define EXP2(x) __builtin_amdgcn_exp2f(x)
#else
#define EXP2(x) exp2f(x)
#endif

__device__ __forceinline__ u16 f2bf(float f) {           // RNE, for cold paths
    u32 u = __float_as_uint(f);
    u32 r = u + 0x7FFFu + ((u >> 16) & 1u);
    return (u16)(r >> 16);
}
__device__ __forceinline__ float bf2f(u16 h) { return __uint_as_float(((u32)h) << 16); }
__device__ __forceinline__ void splitbf(float v, u16& hi, u16& lo) {
    hi = f2bf(v);
    lo = f2bf(v - bf2f(hi));
}
__device__ __forceinline__ u16 cvt1(float f) {           // native convert (RNE)
    __hip_bfloat16 b = __float2bfloat16(f);
    return *reinterpret_cast<u16*>(&b);
}
__device__ __forceinline__ s8 ld8(const u16* p) { return *reinterpret_cast<const s8*>(p); }
__device__ __forceinline__ u32 bfpair(float a, float b) {
    return (u32)cvt1(a) | ((u32)cvt1(b) << 16);
}

// ---------------------------------------------------------------------------
// Phase 0a: build transposed+split QKV weight matrix Wt[COUT][DINP]
// ---------------------------------------------------------------------------
__global__ void k_wprep(const float* __restrict__ wq, const float* __restrict__ wk,
                        const float* __restrict__ wv,
                        u16* __restrict__ wtHi, u16* __restrict__ wtLo) {
    int c = blockIdx.x;                   // 0..767
    int s = c >> 8, h = (c >> 5) & 7, hd = c & 31;
    const float* w = (s == 0) ? wq : (s == 1) ? wk : wv;
    for (int k = threadIdx.x; k < DINP; k += blockDim.x) {
        float val = (k < DIN) ? w[(h * DIN + k) * HD + hd] : 0.0f;
        u16 hi, lo; splitbf(val, hi, lo);
        wtHi[c * DINP + k] = hi;
        wtLo[c * DINP + k] = lo;
    }
}

// ---------------------------------------------------------------------------
// Phase 0b: woT[c][k] = wo[k][c] (bf16)
// ---------------------------------------------------------------------------
__global__ void k_woprep(const float* __restrict__ wo, u16* __restrict__ woT) {
    int c = blockIdx.x;
    int k = threadIdx.x;                  // blockDim = 256
    woT[c * 256 + k] = f2bf(wo[k * 256 + c]);
}

// ---------------------------------------------------------------------------
// Phase 1: featurize. One 64-lane wave per row.
// ---------------------------------------------------------------------------
__global__ __launch_bounds__(64) void k_featurize(const float* __restrict__ x,
                                                  const int* __restrict__ coords,
                                                  u16* __restrict__ xcHi,
                                                  u16* __restrict__ xcLo) {
    int row = blockIdx.x;
    int l = threadIdx.x;
    f4 v = *reinterpret_cast<const f4*>(x + row * 256 + 4 * l);
    float ss = v[0] * v[0] + v[1] * v[1] + v[2] * v[2] + v[3] * v[3];
#pragma unroll
    for (int m = 1; m < 64; m <<= 1) ss += __shfl_xor(ss, m);
    float inv = 1.0f / (sqrtf(ss) + 1e-6f);
#pragma unroll
    for (int j = 0; j < 4; ++j) {
        u16 hi, lo; splitbf(v[j] * inv, hi, lo);
        xcHi[row * DINP + 4 * l + j] = hi;
        xcLo[row * DINP + 4 * l + j] = lo;
    }
    if (l < 32) {
        int col = 256 + l;
        float val = 0.0f;
        if (col < DIN) {
            float c = (float)coords[row * 3 + (col - 256)];
            val = fminf(fmaxf(c, -100.0f), 100.0f);
        }
        u16 hi, lo; splitbf(val, hi, lo);
        xcHi[row * DINP + col] = hi;
        xcLo[row * DINP + col] = lo;
    }
}

// ---------------------------------------------------------------------------
// Phase 2: QKV GEMM  [4096 x DINP] x [DINP x 768] with 3-MFMA emulation.
// q (pre-scaled by SCL2), k row-major [h][n][hd] (hi/lo);
// v tiled [h][n>>4][hd][n&15] (bf16).
// ---------------------------------------------------------------------------
__global__ __launch_bounds__(256) void k_qkv(
        const u16* __restrict__ xcHi, const u16* __restrict__ xcLo,
        const u16* __restrict__ wtHi, const u16* __restrict__ wtLo,
        const float* __restrict__ bq, const float* __restrict__ bk,
        const float* __restrict__ bv,
        u16* __restrict__ qHi, u16* __restrict__ qLo,
        u16* __restrict__ kHi, u16* __restrict__ kLo,
        u16* __restrict__ vt2) {
    int w = threadIdx.x >> 6, l = threadIdx.x & 63;
    int lr = l & 15, lg = l >> 4;
    int r0 = blockIdx.x * 64 + w * 16;    // wave's row base
    int c0 = blockIdx.y * 64;             // block's col base

    f4 acc[4] = {};
    const u16* aH = xcHi + (r0 + lr) * DINP + lg * 8;
    const u16* aL = xcLo + (r0 + lr) * DINP + lg * 8;
#pragma unroll
    for (int kk = 0; kk < 9; ++kk) {
        s8 ah = ld8(aH + kk * 32);
        s8 al = ld8(aL + kk * 32);
#pragma unroll
        for (int ct = 0; ct < 4; ++ct) {
            int c = c0 + ct * 16 + lr;
            s8 bh = ld8(wtHi + c * DINP + kk * 32 + lg * 8);
            s8 bl = ld8(wtLo + c * DINP + kk * 32 + lg * 8);
            acc[ct] = MFMA32(al, bh, acc[ct]);
            acc[ct] = MFMA32(ah, bl, acc[ct]);
            acc[ct] = MFMA32(ah, bh, acc[ct]);
        }
    }
#pragma unroll
    for (int ct = 0; ct < 4; ++ct) {
        int c = c0 + ct * 16 + lr;
        int s = c >> 8, h = (c >> 5) & 7, hd = c & 31;
        float bias = ((s == 0) ? bq : (s == 1) ? bk : bv)[h * HD + hd];
#pragma unroll
        for (int r = 0; r < 4; ++r) {
            int n = r0 + lg * 4 + r;
            float val = acc[ct][r] + bias;
            if (s == 0) {
                u16 hi, lo; splitbf(val * SCL2, hi, lo);   // pre-scaled Q
                qHi[(h * NPTS + n) * HD + hd] = hi;
                qLo[(h * NPTS + n) * HD + hd] = lo;
            } else if (s == 1) {
                u16 hi, lo; splitbf(val, hi, lo);
                kHi[(h * NPTS + n) * HD + hd] = hi;
                kLo[(h * NPTS + n) * HD + hd] = lo;
            } else {
                // tiled V^T: [h][key tile][hd][key%16]
                vt2[((size_t)(h * 256 + (n >> 4)) * 32 + hd) * 16 + (n & 15)] = f2bf(val);
            }
        }
    }
}

// ---------------------------------------------------------------------------
// Phase 3: attention, split-K flash-decoding, fixed-scale softmax, 32-row
// Q-tile. Block = 4 waves on one (head, 32 q-rows); wave w handles keys
// [w*1024, (w+1)*1024) in 16 iters of 64 keys. Two 16-row score tiles (A,B)
// share all K and V fragments. Epilogue: butterfly S', LDS sum-combine.
// blockIdx&7 = head -> per-XCD L2 holds one head's K/V.
// ---------------------------------------------------------------------------
__global__ __launch_bounds__(256, 4) void k_attn(
        const u16* __restrict__ qHi, const u16* __restrict__ qLo,
        const u16* __restrict__ kHi, const u16* __restrict__ kLo,
        const u16* __restrict__ vt2,
        u16* __restrict__ catH) {
    __shared__ float cmb[KSPLIT][64][19];  // {SA,o0A[4],o1A[4],SB,o0B[4],o1B[4]}
    int b = blockIdx.x;
    int h = b & 7;                        // head -> XCD affinity
    int qb = b >> 3;                      // 0..127 (32 rows each)
    int w = threadIdx.x >> 6;             // key-split index
    int l = threadIdx.x & 63, lr = l & 15, lg = l >> 4;

    size_t qoff = (size_t)(h * NPTS + qb * QROWS + lr) * HD + lg * 8;
    s8 qh0 = ld8(qHi + qoff);
    s8 ql0 = ld8(qLo + qoff);
    s8 qh1 = ld8(qHi + qoff + 16 * HD);
    s8 ql1 = ld8(qLo + qoff + 16 * HD);

    // hoisted bases (32-bit per-iter offsets)
    const u16* khb = kHi + (size_t)h * NPTS * HD + lr * HD + lg * 8;
    const u16* klb = kLo + (size_t)h * NPTS * HD + lr * HD + lg * 8;
    const u16* vtb = vt2 + (size_t)h * (NPTS / 16) * 512 + lr * 16 + lg * 4;

    float psA0 = 0.0f, psA1 = 0.0f, psA2 = 0.0f, psA3 = 0.0f;
    float psB0 = 0.0f, psB1 = 0.0f, psB2 = 0.0f, psB3 = 0.0f;
    f4 o0A = {}, o1A = {}, o0B = {}, o1B = {};

#pragma unroll 1
    for (int kb = w * (NPTS / KSPLIT / KBLK); kb < (w + 1) * (NPTS / KSPLIT / KBLK); ++kb) {
        // S^T tiles: st*[kt] holds S^T[key = kt*16 + lg*4 + r][q = lr], log2 dom
        f4 stA[4], stB[4];
#pragma unroll
        for (int kt = 0; kt < 4; ++kt) {
            int koff = (kb * KBLK + kt * 16) * HD;
            s8 kh = ld8(khb + koff);
            s8 kl = ld8(klb + koff);
            f4 a = {};
            a = MFMA32(kl, qh0, a);
            a = MFMA32(kh, ql0, a);
            a = MFMA32(kh, qh0, a);
            stA[kt] = a;
            f4 bb = {};
            bb = MFMA32(kl, qh1, bb);
            bb = MFMA32(kh, ql1, bb);
            bb = MFMA32(kh, qh1, bb);
            stB[kt] = bb;
        }
        // p' = 2^(min(s, CLIP2) - 64); accumulate partial sums; pack bf16
        u32 pkA0[4], pkA1[4], pkB0[4], pkB1[4];
#pragma unroll
        for (int kt = 0; kt < 4; ++kt) {
            float a0 = EXP2(fminf(stA[kt][0] - PRESC, CLIP2 - PRESC)); psA0 += a0;
            float a1 = EXP2(fminf(stA[kt][1] - PRESC, CLIP2 - PRESC)); psA1 += a1;
            float a2 = EXP2(fminf(stA[kt][2] - PRESC, CLIP2 - PRESC)); psA2 += a2;
            float a3 = EXP2(fminf(stA[kt][3] - PRESC, CLIP2 - PRESC)); psA3 += a3;
            pkA0[kt] = bfpair(a0, a1);
            pkA1[kt] = bfpair(a2, a3);
            float b0 = EXP2(fminf(stB[kt][0] - PRESC, CLIP2 - PRESC)); psB0 += b0;
            float b1 = EXP2(fminf(stB[kt][1] - PRESC, CLIP2 - PRESC)); psB1 += b1;
            float b2 = EXP2(fminf(stB[kt][2] - PRESC, CLIP2 - PRESC)); psB2 += b2;
            float b3 = EXP2(fminf(stB[kt][3] - PRESC, CLIP2 - PRESC)); psB3 += b3;
            pkB0[kt] = bfpair(b0, b1);
            pkB1[kt] = bfpair(b2, b3);
        }

        // PV: O'^T += V^T . P'^T  (V fragments shared by both q-tiles)
        int vo = kb * 2048;
#if HAVE_MFMA16
#pragma unroll
        for (int kt = 0; kt < 4; ++kt) {
            union { u32 u[2]; s4v v; } puA, puB;
            puA.u[0] = pkA0[kt]; puA.u[1] = pkA1[kt];
            puB.u[0] = pkB0[kt]; puB.u[1] = pkB1[kt];
            s4v v0 = *reinterpret_cast<const s4v*>(vtb + vo + kt * 512);
            s4v v1 = *reinterpret_cast<const s4v*>(vtb + vo + kt * 512 + 256);
            o0A = MFMA16(v0, puA.v, o0A);
            o1A = MFMA16(v1, puA.v, o1A);
            o0B = MFMA16(v0, puB.v, o0B);
            o1B = MFMA16(v1, puB.v, o1B);
        }
#else
        // fallback: assemble 16x16x32 B-frags via shuffles (per q-tile)
        int srcbase = ((lg & 1) * 2) * 16 + lr;
        bool hiQuad = (lg >> 1) != 0;
#pragma unroll
        for (int s = 0; s < 2; ++s) {
            union { u32 u[4]; s8 v; } buA, buB;
#pragma unroll
            for (int wi = 0; wi < 4; ++wi) {
                int src = srcbase + ((wi >> 1) << 4);
                u32 a0 = (u32)__shfl((int)((wi & 1) ? pkA1[2 * s] : pkA0[2 * s]), src);
                u32 a1 = (u32)__shfl((int)((wi & 1) ? pkA1[2 * s + 1] : pkA0[2 * s + 1]), src);
                buA.u[wi] = hiQuad ? a1 : a0;
                u32 b0 = (u32)__shfl((int)((wi & 1) ? pkB1[2 * s] : pkB0[2 * s]), src);
                u32 b1 = (u32)__shfl((int)((wi & 1) ? pkB1[2 * s + 1] : pkB0[2 * s + 1]), src);
                buB.u[wi] = hiQuad ? b1 : b0;
            }
            int t = 2 * s + (lg >> 1);
            const u16* vt = vtb - lr * 16 - lg * 4 + vo + t * 512 + (lg & 1) * 8;
            s8 v0 = ld8(vt + lr * 16);
            s8 v1 = ld8(vt + (16 + lr) * 16);
            o0A = MFMA32(v0, buA.v, o0A);
            o1A = MFMA32(v1, buA.v, o1A);
            o0B = MFMA32(v0, buB.v, o0B);
            o1B = MFMA32(v1, buB.v, o1B);
        }
#endif
    }

    // per-wave: reduce S' across the 4 lane groups (once, not per iter)
    float SA = (psA0 + psA1) + (psA2 + psA3);
    SA += __shfl_xor(SA, 16);
    SA += __shfl_xor(SA, 32);
    float SB = (psB0 + psB1) + (psB2 + psB3);
    SB += __shfl_xor(SB, 16);
    SB += __shfl_xor(SB, 32);

    // deposit per-wave partials (all share the fixed 2^-64 scale)
    float* c = cmb[w][l];
    c[0] = SA;
#pragma unroll
    for (int r = 0; r < 4; ++r) { c[1 + r] = o0A[r]; c[5 + r] = o1A[r]; }
    c[9] = SB;
#pragma unroll
    for (int r = 0; r < 4; ++r) { c[10 + r] = o0B[r]; c[14 + r] = o1B[r]; }
    __syncthreads();

    if (w == 0) {
        float StA = 0.0f, StB = 0.0f;
        f4 O0A = {}, O1A = {}, O0B = {}, O1B = {};
#pragma unroll
        for (int ww = 0; ww < KSPLIT; ++ww) {
            const float* cc = cmb[ww][l];
            StA += cc[0];
            StB += cc[9];
#pragma unroll
            for (int r = 0; r < 4; ++r) {
                O0A[r] += cc[1 + r];
                O1A[r] += cc[5 + r];
                O0B[r] += cc[10 + r];
                O1B[r] += cc[14 + r];
            }
        }
        // reference's +1e-6 on the max-normalized sum perturbs output by
        // <=1e-6 relative -- negligible vs bf16 rounding; plain divide.
        float invA = 1.0f / StA;
        float invB = 1.0f / StB;
        int n = qb * QROWS + lr;
        u16* dstA = catH + n * 256 + h * HD + lg * 4;
        *reinterpret_cast<uint2*>(dstA) =
            make_uint2(bfpair(O0A[0] * invA, O0A[1] * invA),
                       bfpair(O0A[2] * invA, O0A[3] * invA));
        *reinterpret_cast<uint2*>(dstA + 16) =
            make_uint2(bfpair(O1A[0] * invA, O1A[1] * invA),
                       bfpair(O1A[2] * invA, O1A[3] * invA));
        u16* dstB = dstA + 16 * 256;
        *reinterpret_cast<uint2*>(dstB) =
            make_uint2(bfpair(O0B[0] * invB, O0B[1] * invB),
                       bfpair(O0B[2] * invB, O0B[3] * invB));
        *reinterpret_cast<uint2*>(dstB + 16) =
            make_uint2(bfpair(O1B[0] * invB, O1B[1] * invB),
                       bfpair(O1B[2] * invB, O1B[3] * invB));
    }
}

// ---------------------------------------------------------------------------
// Phase 4: out = cat @ wo + bo + x   (bf16 MFMA, fp32 epilogue)
// ---------------------------------------------------------------------------
__global__ __launch_bounds__(256) void k_out(
        const u16* __restrict__ catH, const u16* __restrict__ woT,
        const float* __restrict__ bo, const float* __restrict__ x,
        float* __restrict__ out) {
    int w = threadIdx.x >> 6, l = threadIdx.x & 63;
    int lr = l & 15, lg = l >> 4;
    int r0 = blockIdx.x * 64 + w * 16;
    int c0 = blockIdx.y * 64;
    f4 acc[4] = {};
#pragma unroll
    for (int kk = 0; kk < 8; ++kk) {
        s8 a = ld8(catH + (r0 + lr) * 256 + kk * 32 + lg * 8);
#pragma unroll
        for (int ct = 0; ct < 4; ++ct) {
            s8 b = ld8(woT + (c0 + ct * 16 + lr) * 256 + kk * 32 + lg * 8);
            acc[ct] = MFMA32(a, b, acc[ct]);
        }
    }
#pragma unroll
    for (int ct = 0; ct < 4; ++ct) {
        int c = c0 + ct * 16 + lr;
        float bias = bo[c];
#pragma unroll
        for (int r = 0; r < 4; ++r) {
            int n = r0 + lg * 4 + r;
            out[n * 256 + c] = acc[ct][r] + bias + x[n * 256 + c];
        }
    }
}

// ---------------------------------------------------------------------------
extern "C" void kernel_launch(void* const* d_in, const int* in_sizes, int n_in,
                              void* d_out, int out_size, void* d_ws, size_t ws_size,
                              hipStream_t stream) {
    const float* x      = (const float*)d_in[0];
    const int*   coords = (const int*)d_in[1];
    const float* wq     = (const float*)d_in[2];
    const float* bq     = (const float*)d_in[3];
    const float* wk     = (const float*)d_in[4];
    const float* bk     = (const float*)d_in[5];
    const float* wv     = (const float*)d_in[6];
    const float* bv     = (const float*)d_in[7];
    const float* wo     = (const float*)d_in[8];
    const float* bo     = (const float*)d_in[9];
    float* out = (float*)d_out;

    char* ws = (char*)d_ws;
    size_t off = 0;
    auto alloc = [&](size_t bytes) {
        char* p = ws + off;
        off = (off + bytes + 255) & ~(size_t)255;
        return p;
    };
    u16* xcHi = (u16*)alloc((size_t)NPTS * DINP * 2);
    u16* xcLo = (u16*)alloc((size_t)NPTS * DINP * 2);
    u16* wtHi = (u16*)alloc((size_t)COUT * DINP * 2);
    u16* wtLo = (u16*)alloc((size_t)COUT * DINP * 2);
    u16* qHi  = (u16*)alloc((size_t)NH * NPTS * HD * 2);
    u16* qLo  = (u16*)alloc((size_t)NH * NPTS * HD * 2);
    u16* kHi  = (u16*)alloc((size_t)NH * NPTS * HD * 2);
    u16* kLo  = (u16*)alloc((size_t)NH * NPTS * HD * 2);
    u16* vt2  = (u16*)alloc((size_t)NH * NPTS * HD * 2);
    u16* catH = (u16*)alloc((size_t)NPTS * 256 * 2);
    u16* woT  = (u16*)alloc((size_t)256 * 256 * 2);
    (void)ws_size; (void)in_sizes; (void)n_in; (void)out_size;

    k_wprep<<<COUT, 64, 0, stream>>>(wq, wk, wv, wtHi, wtLo);
    k_woprep<<<256, 256, 0, stream>>>(wo, woT);
    k_featurize<<<NPTS, 64, 0, stream>>>(x, coords, xcHi, xcLo);
    k_qkv<<<dim3(NPTS / 64, COUT / 64), 256, 0, stream>>>(
        xcHi, xcLo, wtHi, wtLo, bq, bk, bv, qHi, qLo, kHi, kLo, vt2);
    k_attn<<<NPTS / QROWS * NH, 256, 0, stream>>>(qHi, qLo, kHi, kLo, vt2, catH);
    k_out<<<dim3(NPTS / 64, 256 / 64), 256, 0, stream>>>(catH, woT, bo, x, out);
}